// Round 2
// baseline (1585.933 us; speedup 1.0000x reference)
//
#include <hip/hip_runtime.h>
#include <math.h>

#define B_ 2048
#define T_ 512
#define E_ 128
#define C_ 64
#define H_ 32
#define G_ 96   // 3*H
#define D_ 192  // E+C

typedef float f4 __attribute__((ext_vector_type(4)));

// ---------------- K0: transpose W_ih [96][192] -> wt [192][96] ----------------
__global__ void k0_wt(const float* __restrict__ Wih, float* __restrict__ wt) {
    for (int f = threadIdx.x; f < G_ * D_; f += blockDim.x) {
        int g = f / D_, k = f % D_;
        wt[k * G_ + g] = Wih[f];
    }
}

// ---------------- K1: gx[b][t'][96] = x[b,t,:] @ wt + b_ih ----------------
// grid (B/64, Tc/2), block 256. Tile: 64 b x 2 t (=128 rows) x 96 cols, K=192.
__global__ __launch_bounds__(256) void k1_proj(
    const float* __restrict__ emb, const float* __restrict__ ctx,
    const float* __restrict__ wt, const float* __restrict__ bih,
    float* __restrict__ gx, int t0, int Tc)
{
    __shared__ float sX[128 * 36];   // 128 rows x 32 k, pad to 36 (16B-aligned, 4-way max)
    __shared__ float sW[32 * G_];    // 32 k x 96 cols (k uniform across lanes -> no conflict)
    const int tid = threadIdx.x;
    const int rr = tid & 31;         // row base 0..31 (rows rr+32i)
    const int cc = tid >> 5;         // 0..7 (cols cc*12..+12)
    const int b0 = blockIdx.x * 64;
    const int tp = t0 + blockIdx.y * 2;

    float acc[4][12];
    #pragma unroll
    for (int j = 0; j < 12; ++j) {
        float bv = bih[cc * 12 + j];
        #pragma unroll
        for (int i = 0; i < 4; ++i) acc[i][j] = bv;
    }

    const int srow = tid >> 1;                 // 0..127 staging row
    const int sb = b0 + (srow >> 1);
    const int st = tp + (srow & 1);
    const size_t re = ((size_t)sb * T_ + st) * E_;
    const size_t rc = ((size_t)sb * T_ + st) * C_;
    const int koff = (tid & 1) * 16;

    for (int c = 0; c < 6; ++c) {
        const float* src = (c < 4) ? (emb + re + c * 32 + koff)
                                   : (ctx + rc + (c - 4) * 32 + koff);
        f4 x0 = *(const f4*)(src + 0);
        f4 x1 = *(const f4*)(src + 4);
        f4 x2 = *(const f4*)(src + 8);
        f4 x3 = *(const f4*)(src + 12);
        const float* wsrc = wt + (size_t)c * 32 * G_ + tid * 12;
        f4 w0 = *(const f4*)(wsrc + 0);
        f4 w1 = *(const f4*)(wsrc + 4);
        f4 w2 = *(const f4*)(wsrc + 8);
        __syncthreads();   // previous chunk's compute done before overwrite
        *(f4*)&sX[srow * 36 + koff + 0]  = x0;
        *(f4*)&sX[srow * 36 + koff + 4]  = x1;
        *(f4*)&sX[srow * 36 + koff + 8]  = x2;
        *(f4*)&sX[srow * 36 + koff + 12] = x3;
        *(f4*)&sW[tid * 12 + 0] = w0;
        *(f4*)&sW[tid * 12 + 4] = w1;
        *(f4*)&sW[tid * 12 + 8] = w2;
        __syncthreads();
        #pragma unroll
        for (int k4 = 0; k4 < 8; ++k4) {
            f4 xr[4];
            #pragma unroll
            for (int i = 0; i < 4; ++i)
                xr[i] = *(const f4*)&sX[(rr + 32 * i) * 36 + k4 * 4];
            #pragma unroll
            for (int kk = 0; kk < 4; ++kk) {
                const float* wp = &sW[(k4 * 4 + kk) * G_ + cc * 12];
                f4 a  = *(const f4*)(wp + 0);
                f4 bq = *(const f4*)(wp + 4);
                f4 cq = *(const f4*)(wp + 8);
                #pragma unroll
                for (int i = 0; i < 4; ++i) {
                    float xs = xr[i][kk];
                    acc[i][0]  = fmaf(xs, a[0],  acc[i][0]);
                    acc[i][1]  = fmaf(xs, a[1],  acc[i][1]);
                    acc[i][2]  = fmaf(xs, a[2],  acc[i][2]);
                    acc[i][3]  = fmaf(xs, a[3],  acc[i][3]);
                    acc[i][4]  = fmaf(xs, bq[0], acc[i][4]);
                    acc[i][5]  = fmaf(xs, bq[1], acc[i][5]);
                    acc[i][6]  = fmaf(xs, bq[2], acc[i][6]);
                    acc[i][7]  = fmaf(xs, bq[3], acc[i][7]);
                    acc[i][8]  = fmaf(xs, cq[0], acc[i][8]);
                    acc[i][9]  = fmaf(xs, cq[1], acc[i][9]);
                    acc[i][10] = fmaf(xs, cq[2], acc[i][10]);
                    acc[i][11] = fmaf(xs, cq[3], acc[i][11]);
                }
            }
        }
    }
    #pragma unroll
    for (int i = 0; i < 4; ++i) {
        int prow = rr + 32 * i;
        int ob = b0 + (prow >> 1);
        int ot = (tp - t0) + (prow & 1);
        float* dst = gx + ((size_t)ob * Tc + ot) * G_ + cc * 12;
        f4 o0 = {acc[i][0], acc[i][1], acc[i][2],  acc[i][3]};
        f4 o1 = {acc[i][4], acc[i][5], acc[i][6],  acc[i][7]};
        f4 o2 = {acc[i][8], acc[i][9], acc[i][10], acc[i][11]};
        *(f4*)(dst + 0) = o0;
        *(f4*)(dst + 4) = o1;
        *(f4*)(dst + 8) = o2;
    }
}

// ---------------- K2: GRU scan over one T-chunk, wave-per-row ----------------
// grid B/8, block 512 (8 waves). Lane l: gate-row l (r: 0-31, z: 32-63) and row 64+(l&31) (n).
// Occupancy is only 2 waves/SIMD -> dot chains must be ILP-split (4 partial accs)
// or the 4-cyc fma dep latency is exposed (~128 cyc/chain/step).
__global__ __launch_bounds__(512) void k2_scan(
    const float* __restrict__ gx, const float* __restrict__ Whh,
    const float* __restrict__ bhh, float* __restrict__ hbuf,
    const float* __restrict__ W1, const float* __restrict__ b1,
    const float* __restrict__ W2, const float* __restrict__ b2,
    float* __restrict__ out, int t0, int Tc)
{
    const int lane = threadIdx.x & 63;
    const int wv = threadIdx.x >> 6;
    const int b = blockIdx.x * 8 + wv;
    const int j = lane & 31;

    // W_hh rows register-resident: row1 = lane (r/z), row2 = 64+j (n)
    float wr1[32], wr2[32];
    {
        const float* p1 = Whh + lane * H_;
        const float* p2 = Whh + (64 + j) * H_;
        #pragma unroll
        for (int q = 0; q < 8; ++q) {
            f4 a = *(const f4*)(p1 + q * 4);
            f4 c = *(const f4*)(p2 + q * 4);
            wr1[q * 4 + 0] = a[0]; wr1[q * 4 + 1] = a[1];
            wr1[q * 4 + 2] = a[2]; wr1[q * 4 + 3] = a[3];
            wr2[q * 4 + 0] = c[0]; wr2[q * 4 + 1] = c[1];
            wr2[q * 4 + 2] = c[2]; wr2[q * 4 + 3] = c[3];
        }
    }
    const float bh1 = bhh[lane];
    const float bh2 = bhh[64 + j];

    // h replicated wave-uniform (SGPR via readlane); hj = per-lane h_j
    float h[32];
    float hj;
    if (t0 == 0) {
        #pragma unroll
        for (int k = 0; k < 32; ++k) h[k] = 0.f;
        hj = 0.f;
    } else {
        #pragma unroll
        for (int q = 0; q < 8; ++q) {
            f4 a = *(const f4*)&hbuf[b * H_ + q * 4];
            h[q * 4 + 0] = a[0]; h[q * 4 + 1] = a[1];
            h[q * 4 + 2] = a[2]; h[q * 4 + 3] = a[3];
        }
        hj = hbuf[b * H_ + j];
    }

    const float* gp = gx + (size_t)b * Tc * G_;
    float g1 = gp[lane];
    float g2 = gp[64 + j];

    for (int tt = 0; tt < Tc; ++tt) {
        // prefetch next step's gx (hidden under the dots)
        const int tn = (tt + 1 < Tc) ? (tt + 1) : tt;
        const float g1n = gp[(size_t)tn * G_ + lane];
        const float g2n = gp[(size_t)tn * G_ + 64 + j];

        // 4-way ILP-split dot products (8-deep chains instead of 32-deep)
        float s10 = bh1, s11 = 0.f, s12 = 0.f, s13 = 0.f;
        float s20 = bh2, s21 = 0.f, s22 = 0.f, s23 = 0.f;
        #pragma unroll
        for (int k = 0; k < 8; ++k) {
            s10 = fmaf(wr1[k],      h[k],      s10);
            s11 = fmaf(wr1[k + 8],  h[k + 8],  s11);
            s12 = fmaf(wr1[k + 16], h[k + 16], s12);
            s13 = fmaf(wr1[k + 24], h[k + 24], s13);
            s20 = fmaf(wr2[k],      h[k],      s20);
            s21 = fmaf(wr2[k + 8],  h[k + 8],  s21);
            s22 = fmaf(wr2[k + 16], h[k + 16], s22);
            s23 = fmaf(wr2[k + 24], h[k + 24], s23);
        }
        float a1 = (s10 + s11) + (s12 + s13);
        float a2 = (s20 + s21) + (s22 + s23);

        a1 += g1;                                   // r-pre (lanes<32) / z-pre (lanes>=32)
        const float e1 = __expf(-a1);
        const float sg = __fdividef(1.f, 1.f + e1); // r or z
        const float zj = __shfl(sg, 32 + j, 64);    // z_j to all lanes
        float npre = g2 + sg * a2;                  // lanes<32: xn + r*hn (hn has b_hh inside)
        npre = fminf(fmaxf(npre, -30.f), 30.f);
        const float e2 = __expf(-2.f * npre);
        const float nj = __fdividef(1.f - e2, 1.f + e2);   // tanh
        const float hnew = (1.f - zj) * nj + zj * hj;      // valid lanes<32
        hj = __shfl(hnew, j, 64);
        #pragma unroll
        for (int k = 0; k < 32; ++k)
            h[k] = __int_as_float(__builtin_amdgcn_readlane(__float_as_int(hnew), k));
        g1 = g1n; g2 = g2n;
    }

    if (t0 + Tc == T_) {
        // fused head: Linear(32,16) -> ReLU -> Linear(16,1) -> Sigmoid
        const int i = lane & 15;
        const float* w1p = W1 + i * H_;
        float q0 = b1[i], q1 = 0.f, q2 = 0.f, q3 = 0.f;
        #pragma unroll
        for (int k = 0; k < 8; ++k) {
            q0 = fmaf(w1p[k],      h[k],      q0);
            q1 = fmaf(w1p[k + 8],  h[k + 8],  q1);
            q2 = fmaf(w1p[k + 16], h[k + 16], q2);
            q3 = fmaf(w1p[k + 24], h[k + 24], q3);
        }
        float hid = fmaxf((q0 + q1) + (q2 + q3), 0.f);
        float p = W2[i] * hid;
        p += __shfl_xor(p, 1, 64);
        p += __shfl_xor(p, 2, 64);
        p += __shfl_xor(p, 4, 64);
        p += __shfl_xor(p, 8, 64);
        if (lane == 0) {
            const float o = p + b2[0];
            const float e = __expf(-o);
            out[b] = __fdividef(1.f, 1.f + e);
        }
    } else {
        if (lane < 32) hbuf[b * H_ + lane] = hj;
    }
}

extern "C" void kernel_launch(void* const* d_in, const int* in_sizes, int n_in,
                              void* d_out, int out_size, void* d_ws, size_t ws_size,
                              hipStream_t stream)
{
    const float* emb = (const float*)d_in[0];
    const float* ctx = (const float*)d_in[1];
    const float* Wih = (const float*)d_in[2];
    const float* Whh = (const float*)d_in[3];
    const float* bih = (const float*)d_in[4];
    const float* bhh = (const float*)d_in[5];
    const float* W1  = (const float*)d_in[6];
    const float* b1  = (const float*)d_in[7];
    const float* W2  = (const float*)d_in[8];
    const float* b2  = (const float*)d_in[9];
    float* out = (float*)d_out;

    float* wt   = (float*)d_ws;          // 192*96 floats
    float* hbuf = wt + D_ * G_;          // 2048*32 floats
    float* gxw  = hbuf + B_ * H_;        // B*Tc*96 floats

    // Deterministic T-chunking from ws_size: prefer Tc=128 (~101 MB, LLC-friendly)
    const size_t fixed = (size_t)(D_ * G_ + B_ * H_) * 4;
    int Tc = 128;
    while (Tc > 2 && fixed + (size_t)B_ * Tc * G_ * 4 > ws_size) Tc >>= 1;

    hipLaunchKernelGGL(k0_wt, dim3(1), dim3(256), 0, stream, Wih, wt);
    for (int t0 = 0; t0 < T_; t0 += Tc) {
        hipLaunchKernelGGL(k1_proj, dim3(B_ / 64, Tc / 2), dim3(256), 0, stream,
                           emb, ctx, wt, bih, gxw, t0, Tc);
        hipLaunchKernelGGL(k2_scan, dim3(B_ / 8), dim3(512), 0, stream,
                           gxw, Whh, bhh, hbuf, W1, b1, W2, b2, out, t0, Tc);
    }
}

// Round 3
// 1318.158 us; speedup vs baseline: 1.2031x; 1.2031x over previous
//
#include <hip/hip_runtime.h>
#include <math.h>

#define B_ 2048
#define T_ 512
#define E_ 128
#define C_ 64
#define H_ 32
#define G_ 96   // 3*H
#define D_ 192  // E+C

typedef float f4 __attribute__((ext_vector_type(4)));
typedef short s8v __attribute__((ext_vector_type(8)));
typedef int i4 __attribute__((ext_vector_type(4)));

// ---------------- K0: split W_ih into MFMA B-fragment layout, bf16 hi/lo ----
// frag f = s*6+nf (k-slice s, n-frag nf); element (l,e):
//   n = nf*16 + (l&15), k = s*32 + (l>>4)*8 + e
// whi[f*512 + l*8 + e], wlo likewise (wlo contiguous after whi).
__global__ void k0_prep(const float* __restrict__ Wih,
                        unsigned short* __restrict__ whi,
                        unsigned short* __restrict__ wlo) {
    for (int idx = threadIdx.x + blockIdx.x * blockDim.x; idx < 36 * 512;
         idx += blockDim.x * gridDim.x) {
        int f = idx >> 9;
        int l = (idx >> 3) & 63;
        int e = idx & 7;
        int s = f / 6, nf = f % 6;
        int n = nf * 16 + (l & 15);
        int k = s * 32 + ((l >> 4) << 3) + e;
        unsigned int u = __float_as_uint(Wih[n * D_ + k]);
        unsigned int hu = u & 0xFFFF0000u;                    // exact truncate-split
        float lo = __uint_as_float(u) - __uint_as_float(hu);  // exact residual
        whi[idx] = (unsigned short)(hu >> 16);
        wlo[idx] = (unsigned short)(__float_as_uint(lo) >> 16);
    }
}

// ---------------- K1: gx = x @ W_ih^T + b_ih via bf16x2-split MFMA ----------
// grid (B*Tc)/128 blocks, 256 threads (4 waves). Block tile: 128 rows x 96.
// Wave: 32 rows (2 m-frags) x 96 (6 n-frags), K=192 (6 slices of 32).
// 3-term split: hi*Whi + hi*Wlo + lo*Whi  (error ~2^-17 relative).
__global__ __launch_bounds__(256, 2) void k1_mfma(
    const float* __restrict__ emb, const float* __restrict__ ctx,
    const unsigned short* __restrict__ wfrag,  // whi(18432 shorts) ++ wlo(18432)
    const float* __restrict__ bih, float* __restrict__ gx,
    int t0, int tcshift)
{
    __shared__ unsigned short sW[36864];   // 73.7 KB -> 2 blocks/CU
    const int tid = threadIdx.x;
    const int lane = tid & 63;
    const int wv = tid >> 6;
    const int Tc = 1 << tcshift;

    // stage W fragments once (73728 B, 18 x 16B/thread)
    #pragma unroll
    for (int it = 0; it < 18; ++it) {
        int ofs = (it * 256 + tid) * 16;   // bytes
        i4 v = *(const i4*)((const char*)wfrag + ofs);
        *(i4*)((char*)sW + ofs) = v;
    }

    // per-lane A addressing: A-frag row = lane&15, k-sub = (lane>>4)*8
    const int r0 = blockIdx.x * 128 + wv * 32;
    const int lr = lane & 15;
    const int ke = (lane >> 4) << 3;
    size_t abase_e[2], abase_c[2];
    #pragma unroll
    for (int mf = 0; mf < 2; ++mf) {
        int r = r0 + mf * 16 + lr;
        int b = r >> tcshift;
        int tp = t0 + (r & (Tc - 1));
        abase_e[mf] = ((size_t)b * T_ + tp) * E_ + ke;
        abase_c[mf] = ((size_t)b * T_ + tp) * C_ + ke;
    }

    f4 acc[2][6];
    #pragma unroll
    for (int nf = 0; nf < 6; ++nf) {
        float bv = bih[nf * 16 + lr];
        acc[0][nf] = (f4){bv, bv, bv, bv};
        acc[1][nf] = (f4){bv, bv, bv, bv};
    }

    __syncthreads();

    #pragma unroll
    for (int s = 0; s < 6; ++s) {
        // A: 2 frags x 8 fp32, truncate-split to bf16 hi/lo
        s8v ahi[2], alo[2];
        #pragma unroll
        for (int mf = 0; mf < 2; ++mf) {
            const float* ap = (s < 4) ? (emb + abase_e[mf] + s * 32)
                                      : (ctx + abase_c[mf] + (s - 4) * 32);
            f4 x0 = *(const f4*)ap;
            f4 x1 = *(const f4*)(ap + 4);
            #pragma unroll
            for (int e = 0; e < 4; ++e) {
                unsigned int u0 = __float_as_uint(x0[e]);
                unsigned int h0 = u0 & 0xFFFF0000u;
                float l0 = x0[e] - __uint_as_float(h0);
                ahi[mf][e] = (short)(h0 >> 16);
                alo[mf][e] = (short)(__float_as_uint(l0) >> 16);
                unsigned int u1 = __float_as_uint(x1[e]);
                unsigned int h1 = u1 & 0xFFFF0000u;
                float l1 = x1[e] - __uint_as_float(h1);
                ahi[mf][4 + e] = (short)(h1 >> 16);
                alo[mf][4 + e] = (short)(__float_as_uint(l1) >> 16);
            }
        }
        #pragma unroll
        for (int nf = 0; nf < 6; ++nf) {
            const int fo = (s * 6 + nf) * 512 + lane * 8;   // short units
            s8v bhi = *(const s8v*)(sW + fo);
            s8v blo = *(const s8v*)(sW + 18432 + fo);
            #pragma unroll
            for (int mf = 0; mf < 2; ++mf) {
                acc[mf][nf] = __builtin_amdgcn_mfma_f32_16x16x32_bf16(ahi[mf], bhi, acc[mf][nf], 0, 0, 0);
                acc[mf][nf] = __builtin_amdgcn_mfma_f32_16x16x32_bf16(ahi[mf], blo, acc[mf][nf], 0, 0, 0);
                acc[mf][nf] = __builtin_amdgcn_mfma_f32_16x16x32_bf16(alo[mf], bhi, acc[mf][nf], 0, 0, 0);
            }
        }
    }

    // store: D row = (lane>>4)*4 + q (m89-verified), col = lane&15
    const int qr = (lane >> 4) << 2;
    #pragma unroll
    for (int mf = 0; mf < 2; ++mf) {
        int rs = r0 + mf * 16 + qr;
        #pragma unroll
        for (int q = 0; q < 4; ++q) {
            float* gp = gx + (size_t)(rs + q) * G_ + lr;
            #pragma unroll
            for (int nf = 0; nf < 6; ++nf)
                gp[nf * 16] = acc[mf][nf][q];
        }
    }
}

// ---------------- K2: GRU scan over one T-chunk, wave-per-row ----------------
// grid B/8, block 512 (8 waves). Lane l: gate-row l (r: 0-31, z: 32-63) and
// row 64+(l&31) (n). ILP-split dots (8-deep chains); h replicated via readlane.
__global__ __launch_bounds__(512) void k2_scan(
    const float* __restrict__ gx, const float* __restrict__ Whh,
    const float* __restrict__ bhh, float* __restrict__ hbuf,
    const float* __restrict__ W1, const float* __restrict__ b1,
    const float* __restrict__ W2, const float* __restrict__ b2,
    float* __restrict__ out, int t0, int Tc)
{
    const int lane = threadIdx.x & 63;
    const int wv = threadIdx.x >> 6;
    const int b = blockIdx.x * 8 + wv;
    const int j = lane & 31;

    float wr1[32], wr2[32];
    {
        const float* p1 = Whh + lane * H_;
        const float* p2 = Whh + (64 + j) * H_;
        #pragma unroll
        for (int q = 0; q < 8; ++q) {
            f4 a = *(const f4*)(p1 + q * 4);
            f4 c = *(const f4*)(p2 + q * 4);
            wr1[q * 4 + 0] = a[0]; wr1[q * 4 + 1] = a[1];
            wr1[q * 4 + 2] = a[2]; wr1[q * 4 + 3] = a[3];
            wr2[q * 4 + 0] = c[0]; wr2[q * 4 + 1] = c[1];
            wr2[q * 4 + 2] = c[2]; wr2[q * 4 + 3] = c[3];
        }
    }
    const float bh1 = bhh[lane];
    const float bh2 = bhh[64 + j];

    float h[32];
    float hj;
    if (t0 == 0) {
        #pragma unroll
        for (int k = 0; k < 32; ++k) h[k] = 0.f;
        hj = 0.f;
    } else {
        #pragma unroll
        for (int q = 0; q < 8; ++q) {
            f4 a = *(const f4*)&hbuf[b * H_ + q * 4];
            h[q * 4 + 0] = a[0]; h[q * 4 + 1] = a[1];
            h[q * 4 + 2] = a[2]; h[q * 4 + 3] = a[3];
        }
        hj = hbuf[b * H_ + j];
    }

    const float* gp = gx + (size_t)b * Tc * G_;
    float g1 = gp[lane];
    float g2 = gp[64 + j];

    for (int tt = 0; tt < Tc; ++tt) {
        const int tn = (tt + 1 < Tc) ? (tt + 1) : tt;
        const float g1n = gp[(size_t)tn * G_ + lane];
        const float g2n = gp[(size_t)tn * G_ + 64 + j];

        float s10 = bh1, s11 = 0.f, s12 = 0.f, s13 = 0.f;
        float s20 = bh2, s21 = 0.f, s22 = 0.f, s23 = 0.f;
        #pragma unroll
        for (int k = 0; k < 8; ++k) {
            s10 = fmaf(wr1[k],      h[k],      s10);
            s11 = fmaf(wr1[k + 8],  h[k + 8],  s11);
            s12 = fmaf(wr1[k + 16], h[k + 16], s12);
            s13 = fmaf(wr1[k + 24], h[k + 24], s13);
            s20 = fmaf(wr2[k],      h[k],      s20);
            s21 = fmaf(wr2[k + 8],  h[k + 8],  s21);
            s22 = fmaf(wr2[k + 16], h[k + 16], s22);
            s23 = fmaf(wr2[k + 24], h[k + 24], s23);
        }
        float a1 = (s10 + s11) + (s12 + s13);
        float a2 = (s20 + s21) + (s22 + s23);

        a1 += g1;
        const float e1 = __expf(-a1);
        const float sg = __fdividef(1.f, 1.f + e1);   // r (lanes<32) / z (lanes>=32)
        const float zj = __shfl(sg, 32 + j, 64);
        float npre = g2 + sg * a2;
        npre = fminf(fmaxf(npre, -30.f), 30.f);
        const float e2 = __expf(-2.f * npre);
        const float nj = __fdividef(1.f - e2, 1.f + e2);
        const float hnew = (1.f - zj) * nj + zj * hj;  // valid on lanes<32
        hj = hnew;                                     // lanes<32 only consumed
        #pragma unroll
        for (int k = 0; k < 32; ++k)
            h[k] = __int_as_float(__builtin_amdgcn_readlane(__float_as_int(hnew), k));
        g1 = g1n; g2 = g2n;
    }

    if (t0 + Tc == T_) {
        const int i = lane & 15;
        const float* w1p = W1 + i * H_;
        float q0 = b1[i], q1 = 0.f, q2 = 0.f, q3 = 0.f;
        #pragma unroll
        for (int k = 0; k < 8; ++k) {
            q0 = fmaf(w1p[k],      h[k],      q0);
            q1 = fmaf(w1p[k + 8],  h[k + 8],  q1);
            q2 = fmaf(w1p[k + 16], h[k + 16], q2);
            q3 = fmaf(w1p[k + 24], h[k + 24], q3);
        }
        float hid = fmaxf((q0 + q1) + (q2 + q3), 0.f);
        float p = W2[i] * hid;
        p += __shfl_xor(p, 1, 64);
        p += __shfl_xor(p, 2, 64);
        p += __shfl_xor(p, 4, 64);
        p += __shfl_xor(p, 8, 64);
        if (lane == 0) {
            const float o = p + b2[0];
            const float e = __expf(-o);
            out[b] = __fdividef(1.f, 1.f + e);
        }
    } else {
        if (lane < 32) hbuf[b * H_ + lane] = hj;
    }
}

extern "C" void kernel_launch(void* const* d_in, const int* in_sizes, int n_in,
                              void* d_out, int out_size, void* d_ws, size_t ws_size,
                              hipStream_t stream)
{
    const float* emb = (const float*)d_in[0];
    const float* ctx = (const float*)d_in[1];
    const float* Wih = (const float*)d_in[2];
    const float* Whh = (const float*)d_in[3];
    const float* bih = (const float*)d_in[4];
    const float* bhh = (const float*)d_in[5];
    const float* W1  = (const float*)d_in[6];
    const float* b1  = (const float*)d_in[7];
    const float* W2  = (const float*)d_in[8];
    const float* b2  = (const float*)d_in[9];
    float* out = (float*)d_out;

    unsigned short* whi = (unsigned short*)d_ws;     // 18432 shorts
    unsigned short* wlo = whi + 18432;               // 18432 shorts (contiguous)
    float* hbuf = (float*)(wlo + 18432);             // byte 73728, 16B-aligned
    float* gxw  = hbuf + B_ * H_;                    // byte 335872, 16B-aligned

    const size_t fixed = 73728 + (size_t)B_ * H_ * 4;
    int Tc = 128, tcshift = 7;
    while (Tc > 8 && fixed + (size_t)B_ * Tc * G_ * 4 > ws_size) { Tc >>= 1; --tcshift; }

    hipLaunchKernelGGL(k0_prep, dim3(32), dim3(256), 0, stream, Wih, whi, wlo);
    for (int t0 = 0; t0 < T_; t0 += Tc) {
        hipLaunchKernelGGL(k1_mfma, dim3((B_ * Tc) / 128), dim3(256), 0, stream,
                           emb, ctx, whi, bih, gxw, t0, tcshift);
        hipLaunchKernelGGL(k2_scan, dim3(B_ / 8), dim3(512), 0, stream,
                           gxw, Whh, bhh, hbuf, W1, b1, W2, b2, out, t0, Tc);
    }
}